// Round 11
// baseline (91.267 us; speedup 1.0000x reference)
//
#include <hip/hip_runtime.h>
#include <hip/hip_bf16.h>
#include <math.h>

// Problem constants
#define NB 2
#define NC 19      // classes
#define NH 128
#define NW 128
#define NCF 64     // feature channels
#define NHE 64     // ema logits H/W
#define NHX 32     // x_ema H/W
#define EPSC 1e-8f

// d_ws: acc[0]=sum(lp), acc[1]=sum(ln), acc[2]=mask count
__global__ void pfst_init(float* __restrict__ acc) {
    acc[0] = 0.f; acc[1] = 0.f; acc[2] = 0.f;
}

// Accumulate val * bilinear_upsample(ema)[tap k] into accv[0..18]. Runtime k.
__device__ __forceinline__ void gather_acc(const float* __restrict__ Lb,
                                           int k, float val, int h, int w,
                                           float (&accv)[NC]) {
    int i = k / 7, j = k - i * 7;
    int py = h + 2 * i - 6, px = w + 2 * j - 6;
    if ((unsigned)py < 128u && (unsigned)px < 128u) {
        // bilinear half-pixel: src coord = p*0.5 - 0.25
        int iy0 = (py - 1) >> 1; float ty = (py & 1) ? 0.25f : 0.75f;
        int ix0 = (px - 1) >> 1; float tx = (px & 1) ? 0.25f : 0.75f;
        int y0 = iy0 < 0 ? 0 : iy0;
        int y1 = (iy0 + 1) > 63 ? 63 : (iy0 + 1);
        int x0 = ix0 < 0 ? 0 : ix0;
        int x1 = (ix0 + 1) > 63 ? 63 : (ix0 + 1);
        float w00 = (1.f - ty) * (1.f - tx), w01 = (1.f - ty) * tx;
        float w10 = ty * (1.f - tx),         w11 = ty * tx;
        int o00 = y0 * 64 + x0, o01 = y0 * 64 + x1;
        int o10 = y1 * 64 + x0, o11 = y1 * 64 + x1;
        #pragma unroll
        for (int c = 0; c < NC; c++) {
            const float* Lc = Lb + c * (NHE * NHE);
            float g = w00 * Lc[o00] + w01 * Lc[o01] + w10 * Lc[o10] + w11 * Lc[o11];
            accv[c] += val * g;
        }
    }
}

__global__ __launch_bounds__(64) void pfst_main(
    const float* __restrict__ trg, const float* __restrict__ ema,
    const float* __restrict__ xe,  const float* __restrict__ mix,
    float* __restrict__ acc)
{
    int p = blockIdx.x * 64 + threadIdx.x;          // < 32768
    int b = p >> 14; int rem = p & 16383;
    int h = rem >> 7; int w = rem & 127;

    float mval = mix[(b << 14) + rem];
    bool active = mval < 0.5f;                       // (1 - mix) > 0.5
    float lp = 0.f, ln = 0.f, cm = active ? 1.f : 0.f;

    if (active) {
        // ---------- Phase 1: per-cell dot products (<=16 distinct cells) ----------
        const float* Xb = xe + b * NCF * NHX * NHX;
        int yc = h >> 2, xc = w >> 2;
        int by = (h - 6) >> 2, bx = (w - 6) >> 2;

        int offs[16];
        #pragma unroll
        for (int a = 0; a < 4; a++) {
            int cy = by + a; cy = cy < 0 ? 0 : (cy > 31 ? 31 : cy);
            #pragma unroll
            for (int d = 0; d < 4; d++) {
                int cx2 = bx + d; cx2 = cx2 < 0 ? 0 : (cx2 > 31 ? 31 : cx2);
                offs[a * 4 + d] = cy * 32 + cx2;
            }
        }
        int coff = yc * 32 + xc;

        float dotc[16], dotu[16], dcc = 0.f;
        #pragma unroll
        for (int e = 0; e < 16; e++) { dotc[e] = 0.f; dotu[e] = 0.f; }

        for (int c = 0; c < NCF; c++) {
            const float* Xc = Xb + c * (NHX * NHX);
            float cv = Xc[coff];
            dcc += cv * cv;
            #pragma unroll
            for (int e = 0; e < 16; e++) {
                float v = Xc[offs[e]];
                dotc[e] += v * cv;
                dotu[e] += v * v;
            }
        }

        float invc = 1.f / fmaxf(sqrtf(dcc), EPSC);
        float scell[16];
        #pragma unroll
        for (int e = 0; e < 16; e++)
            scell[e] = dotc[e] * invc / fmaxf(sqrtf(dotu[e]), EPSC);

        // ---------- Phase 2: expand to 49 sims ----------
        const int QA[7] = {0, 0, 1, 1, 2, 2, 3};
        const int QB[7] = {0, 1, 1, 2, 2, 3, 3};
        bool ry = (h & 3) >= 2, rx = (w & 3) >= 2;

        float sims[49];
        #pragma unroll
        for (int i = 0; i < 7; i++) {
            int py = h + 2 * i - 6;
            bool vy = (unsigned)py < 128u;
            float srow[4];
            #pragma unroll
            for (int d = 0; d < 4; d++)
                srow[d] = ry ? scell[QA[i] * 4 + d] : scell[QB[i] * 4 + d];
            #pragma unroll
            for (int j = 0; j < 7; j++) {
                int px = w + 2 * j - 6;
                bool vx = (unsigned)px < 128u;
                float v = rx ? srow[QA[j]] : srow[QB[j]];
                sims[i * 7 + j] = (vy && vx) ? v : 0.f;
            }
        }

        const float* Lb = ema + b * NC * NHE * NHE;
        float apos[NC], aneg[NC];
        #pragma unroll
        for (int c = 0; c < NC; c++) { apos[c] = 0.f; aneg[c] = 0.f; }

        // ---------- Phase 3+4 fused: select tap, gather immediately ----------
        // Pos: top-9 by value, lowest-index ties (matches lax.top_k).
        {
            unsigned lo = 0u, hi = 0u;
            #pragma unroll 1
            for (int t = 0; t < 9; t++) {
                float best = -3.4e38f; int bi = 0;
                #pragma unroll
                for (int k = 0; k < 49; k++) {
                    bool freek = (k < 32) ? !((lo >> k) & 1u) : !((hi >> (k - 32)) & 1u);
                    if (freek && sims[k] > best) { best = sims[k]; bi = k; }
                }
                if (bi < 32) lo |= 1u << bi; else hi |= 1u << (bi - 32);
                gather_acc(Lb, bi, best, h, w, apos);
            }
        }
        // Neg: 8 smallest sims, lowest-index ties (== top_k(-sim, 8)).
        {
            unsigned lo = 0u, hi = 0u;
            #pragma unroll 1
            for (int t = 0; t < 8; t++) {
                float best = 3.4e38f; int bi = 0;
                #pragma unroll
                for (int k = 0; k < 49; k++) {
                    bool freek = (k < 32) ? !((lo >> k) & 1u) : !((hi >> (k - 32)) & 1u);
                    if (freek && sims[k] < best) { best = sims[k]; bi = k; }
                }
                if (bi < 32) lo |= 1u << bi; else hi |= 1u << (bi - 32);
                gather_acc(Lb, bi, best, h, w, aneg);
            }
        }

        // ---------- Phase 5: softmax + BCE-with-logits, fused ----------
        float mp = -3.4e38f, mn = -3.4e38f;
        #pragma unroll
        for (int c = 0; c < NC; c++) { mp = fmaxf(mp, apos[c]); mn = fmaxf(mn, aneg[c]); }
        float Zp = 0.f, Sp = 0.f, Zn = 0.f, Sn = 0.f, Bs = 0.f;
        const float* Tb = trg + b * NC * (NH * NW) + (h << 7) + w;
        #pragma unroll
        for (int c = 0; c < NC; c++) {
            float x = Tb[c * (NH * NW)];
            float ep = expf(apos[c] - mp); Zp += ep; Sp += ep * x;
            float en = expf(aneg[c] - mn); Zn += en; Sn += en * x;
            float ls = fminf(x, 0.f) - log1pf(expf(-fabsf(x)));  // log_sigmoid(x)
            Bs += x - ls;
        }
        lp = Bs - Sp / Zp;        // sum_c bce(x, pl_pos)
        ln = Sn / Zn - Bs;        // sum_c -bce(x, pl_neg)
    }

    // ---------- Reduce within wave, then atomics ----------
    #pragma unroll
    for (int off = 32; off > 0; off >>= 1) {
        lp += __shfl_down(lp, off);
        ln += __shfl_down(ln, off);
        cm += __shfl_down(cm, off);
    }
    if ((threadIdx.x & 63) == 0) {
        atomicAdd(acc + 0, lp);
        atomicAdd(acc + 1, ln);
        atomicAdd(acc + 2, cm);
    }
}

// OUTPUT DTYPE DECODE (R0-R10, exact fit of all 11 observations): d_out is
// FLOAT32[2] (reference returns jnp.float32; harness contract "else float*").
// ref = [loss_pos, 0.1*loss_neg]. Prior rounds' two bf16 halves at bytes 0-3
// concatenated into f32 0x3F4EBDA5 = 0.8076 (passing slot 0 by luck) while
// f32 slot 1 (bytes 4-7) was never written -> constant 0.0805664 error.
// R1's [pos,neg] byte order formed 0xBDA53F4E = -0.0806 -> the 0.885 error.
__global__ void pfst_final(const float* __restrict__ acc, float* __restrict__ out) {
    float denom = acc[2] * (float)NC;
    out[0] = acc[0] / denom;              // loss_pos * W_POS(=1.0)
    out[1] = acc[1] / denom * 0.1f;       // loss_neg * W_NEG(=0.1)
}

extern "C" void kernel_launch(void* const* d_in, const int* in_sizes, int n_in,
                              void* d_out, int out_size, void* d_ws, size_t ws_size,
                              hipStream_t stream) {
    const float* trg = (const float*)d_in[0];   // [2,19,128,128]
    const float* ema = (const float*)d_in[1];   // [2,19,64,64]
    const float* xe  = (const float*)d_in[2];   // [2,64,32,32]
    const float* mix = (const float*)d_in[3];   // [2,1,128,128]
    float* acc = (float*)d_ws;
    float* out = (float*)d_out;

    hipLaunchKernelGGL(pfst_init, dim3(1), dim3(1), 0, stream, acc);
    hipLaunchKernelGGL(pfst_main, dim3((NB * NH * NW) / 64), dim3(64), 0, stream,
                       trg, ema, xe, mix, acc);
    hipLaunchKernelGGL(pfst_final, dim3(1), dim3(1), 0, stream, acc, out);
}

// Round 12
// 70.246 us; speedup vs baseline: 1.2993x; 1.2993x over previous
//
#include <hip/hip_runtime.h>
#include <hip/hip_bf16.h>
#include <math.h>

// Problem constants
#define NB 2
#define NC 19      // classes
#define NH 128
#define NW 128
#define NCF 64     // feature channels
#define NHE 64     // ema logits H/W
#define NHX 32     // x_ema H/W
#define EPSC 1e-8f

// d_ws: acc[0]=sum(lp), acc[1]=sum(ln), acc[2]=mask count
__global__ void pfst_init(float* __restrict__ acc) {
    acc[0] = 0.f; acc[1] = 0.f; acc[2] = 0.f;
}

// Quad-split gather: accumulate val * bilinear(ema)[tap k] into this lane's
// classes {l, l+4, ...}. All 4 lanes compute the same weights (cheap).
__device__ __forceinline__ void gather_quad(const float* __restrict__ Lb,
                                            int k, float val, int h, int w,
                                            int l, float (&accv)[5]) {
    int i = k / 7, j = k - i * 7;
    int py = h + 2 * i - 6, px = w + 2 * j - 6;
    if ((unsigned)py < 128u && (unsigned)px < 128u) {
        // bilinear half-pixel: src coord = p*0.5 - 0.25
        int iy0 = (py - 1) >> 1; float ty = (py & 1) ? 0.25f : 0.75f;
        int ix0 = (px - 1) >> 1; float tx = (px & 1) ? 0.25f : 0.75f;
        int y0 = iy0 < 0 ? 0 : iy0;
        int y1 = (iy0 + 1) > 63 ? 63 : (iy0 + 1);
        int x0 = ix0 < 0 ? 0 : ix0;
        int x1 = (ix0 + 1) > 63 ? 63 : (ix0 + 1);
        float w00 = (1.f - ty) * (1.f - tx), w01 = (1.f - ty) * tx;
        float w10 = ty * (1.f - tx),         w11 = ty * tx;
        int o00 = y0 * 64 + x0, o01 = y0 * 64 + x1;
        int o10 = y1 * 64 + x0, o11 = y1 * 64 + x1;
        #pragma unroll
        for (int jc = 0; jc < 5; jc++) {
            int c = l + 4 * jc;
            if (c < NC) {
                const float* Lc = Lb + c * (NHE * NHE);
                float g = w00 * Lc[o00] + w01 * Lc[o01] + w10 * Lc[o10] + w11 * Lc[o11];
                accv[jc] += val * g;
            }
        }
    }
}

// 4 lanes per pixel: lane l of a quad covers channels [16l,16l+16) in phase 1
// and classes {l,l+4,...} in phases 4-5. Phases 2-3 (sims + top-k selection)
// run redundantly per lane — identical to the proven serial code, keeping
// sims[] compile-time-indexed (registers) and tie semantics exact.
__global__ __launch_bounds__(256) void pfst_main(
    const float* __restrict__ trg, const float* __restrict__ ema,
    const float* __restrict__ xe,  const float* __restrict__ mix,
    float* __restrict__ acc)
{
    int tid = threadIdx.x;
    int l = tid & 3;                      // lane in quad
    int q = tid >> 2;                     // pixel slot in block (0..63)
    int p = blockIdx.x * 64 + q;          // < 32768
    int b = p >> 14; int rem = p & 16383;
    int h = rem >> 7; int w = rem & 127;

    float mval = mix[(b << 14) + rem];
    bool active = mval < 0.5f;            // (1 - mix) > 0.5
    float lp = 0.f, ln = 0.f;
    float cm = (active && l == 0) ? 1.f : 0.f;

    if (active) {
        // ---------- Phase 1: cell dots, channels split 16/lane ----------
        const float* Xb = xe + b * NCF * NHX * NHX;
        int yc = h >> 2, xc = w >> 2;
        int by = (h - 6) >> 2, bx = (w - 6) >> 2;

        int offs[16];
        #pragma unroll
        for (int a = 0; a < 4; a++) {
            int cy = by + a; cy = cy < 0 ? 0 : (cy > 31 ? 31 : cy);
            #pragma unroll
            for (int d = 0; d < 4; d++) {
                int cx2 = bx + d; cx2 = cx2 < 0 ? 0 : (cx2 > 31 ? 31 : cx2);
                offs[a * 4 + d] = cy * 32 + cx2;
            }
        }
        int coff = yc * 32 + xc;

        float dotc[16], dotu[16], dcc = 0.f;
        #pragma unroll
        for (int e = 0; e < 16; e++) { dotc[e] = 0.f; dotu[e] = 0.f; }

        const float* Xl = Xb + (l << 4) * (NHX * NHX);   // lane's 16 channels
        for (int cc = 0; cc < 16; cc++) {
            const float* Xc = Xl + cc * (NHX * NHX);
            float cv = Xc[coff];
            dcc += cv * cv;
            #pragma unroll
            for (int e = 0; e < 16; e++) {
                float v = Xc[offs[e]];
                dotc[e] += v * cv;
                dotu[e] += v * v;
            }
        }
        // quad-reduce the 33 partial sums
        #pragma unroll
        for (int e = 0; e < 16; e++) {
            dotc[e] += __shfl_xor(dotc[e], 1); dotc[e] += __shfl_xor(dotc[e], 2);
            dotu[e] += __shfl_xor(dotu[e], 1); dotu[e] += __shfl_xor(dotu[e], 2);
        }
        dcc += __shfl_xor(dcc, 1); dcc += __shfl_xor(dcc, 2);

        float invc = 1.f / fmaxf(sqrtf(dcc), EPSC);
        float scell[16];
        #pragma unroll
        for (int e = 0; e < 16; e++)
            scell[e] = dotc[e] * invc / fmaxf(sqrtf(dotu[e]), EPSC);

        // ---------- Phase 2: expand to 49 sims (redundant per lane) ----------
        const int QA[7] = {0, 0, 1, 1, 2, 2, 3};
        const int QB[7] = {0, 1, 1, 2, 2, 3, 3};
        bool ry = (h & 3) >= 2, rx = (w & 3) >= 2;

        float sims[49];
        #pragma unroll
        for (int i = 0; i < 7; i++) {
            int py = h + 2 * i - 6;
            bool vy = (unsigned)py < 128u;
            float srow[4];
            #pragma unroll
            for (int d = 0; d < 4; d++)
                srow[d] = ry ? scell[QA[i] * 4 + d] : scell[QB[i] * 4 + d];
            #pragma unroll
            for (int j = 0; j < 7; j++) {
                int px = w + 2 * j - 6;
                bool vx = (unsigned)px < 128u;
                float v = rx ? srow[QA[j]] : srow[QB[j]];
                sims[i * 7 + j] = (vy && vx) ? v : 0.f;
            }
        }

        const float* Lb = ema + b * NC * NHE * NHE;
        float ap[5], an[5];
        #pragma unroll
        for (int jc = 0; jc < 5; jc++) { ap[jc] = 0.f; an[jc] = 0.f; }

        // ---------- Phase 3+4: selection (proven code) + quad-split gather ----
        // Pos: top-9 by value, lowest-index ties (matches lax.top_k).
        {
            unsigned lo = 0u, hi = 0u;
            #pragma unroll 1
            for (int t = 0; t < 9; t++) {
                float best = -3.4e38f; int bi = 0;
                #pragma unroll
                for (int k = 0; k < 49; k++) {
                    bool freek = (k < 32) ? !((lo >> k) & 1u) : !((hi >> (k - 32)) & 1u);
                    if (freek && sims[k] > best) { best = sims[k]; bi = k; }
                }
                if (bi < 32) lo |= 1u << bi; else hi |= 1u << (bi - 32);
                gather_quad(Lb, bi, best, h, w, l, ap);
            }
        }
        // Neg: 8 smallest sims, lowest-index ties (== top_k(-sim, 8)).
        {
            unsigned lo = 0u, hi = 0u;
            #pragma unroll 1
            for (int t = 0; t < 8; t++) {
                float best = 3.4e38f; int bi = 0;
                #pragma unroll
                for (int k = 0; k < 49; k++) {
                    bool freek = (k < 32) ? !((lo >> k) & 1u) : !((hi >> (k - 32)) & 1u);
                    if (freek && sims[k] < best) { best = sims[k]; bi = k; }
                }
                if (bi < 32) lo |= 1u << bi; else hi |= 1u << (bi - 32);
                gather_quad(Lb, bi, best, h, w, l, an);
            }
        }

        // ---------- Phase 5: softmax + BCE, classes split across quad ----------
        float mp = -3.4e38f, mn = -3.4e38f;
        #pragma unroll
        for (int jc = 0; jc < 5; jc++) {
            int c = l + 4 * jc;
            if (c < NC) { mp = fmaxf(mp, ap[jc]); mn = fmaxf(mn, an[jc]); }
        }
        mp = fmaxf(mp, __shfl_xor(mp, 1)); mp = fmaxf(mp, __shfl_xor(mp, 2));
        mn = fmaxf(mn, __shfl_xor(mn, 1)); mn = fmaxf(mn, __shfl_xor(mn, 2));

        float Zp = 0.f, Sp = 0.f, Zn = 0.f, Sn = 0.f, Bs = 0.f;
        const float* Tb = trg + b * NC * (NH * NW) + (h << 7) + w;
        #pragma unroll
        for (int jc = 0; jc < 5; jc++) {
            int c = l + 4 * jc;
            if (c < NC) {
                float x = Tb[c * (NH * NW)];
                float ep = expf(ap[jc] - mp); Zp += ep; Sp += ep * x;
                float en = expf(an[jc] - mn); Zn += en; Sn += en * x;
                float ls = fminf(x, 0.f) - log1pf(expf(-fabsf(x)));  // log_sigmoid
                Bs += x - ls;
            }
        }
        #pragma unroll
        for (int s = 1; s <= 2; s <<= 1) {
            Zp += __shfl_xor(Zp, s); Sp += __shfl_xor(Sp, s);
            Zn += __shfl_xor(Zn, s); Sn += __shfl_xor(Sn, s);
            Bs += __shfl_xor(Bs, s);
        }
        lp = Bs - Sp / Zp;        // sum_c bce(x, pl_pos)
        ln = Sn / Zn - Bs;        // sum_c -bce(x, pl_neg)
        if (l != 0) { lp = 0.f; ln = 0.f; }   // one contribution per pixel
    }

    // ---------- Wave reduce, then block reduce, then 3 atomics ----------
    #pragma unroll
    for (int off = 32; off > 0; off >>= 1) {
        lp += __shfl_down(lp, off);
        ln += __shfl_down(ln, off);
        cm += __shfl_down(cm, off);
    }
    __shared__ float red[4][3];
    int wid = tid >> 6;
    if ((tid & 63) == 0) { red[wid][0] = lp; red[wid][1] = ln; red[wid][2] = cm; }
    __syncthreads();
    if (tid == 0) {
        float a0 = red[0][0] + red[1][0] + red[2][0] + red[3][0];
        float a1 = red[0][1] + red[1][1] + red[2][1] + red[3][1];
        float a2 = red[0][2] + red[1][2] + red[2][2] + red[3][2];
        atomicAdd(acc + 0, a0);
        atomicAdd(acc + 1, a1);
        atomicAdd(acc + 2, a2);
    }
}

// Output: FLOAT32[2] = [loss_pos, 0.1*loss_neg] (decoded R0-R10, verified R11).
__global__ void pfst_final(const float* __restrict__ acc, float* __restrict__ out) {
    float denom = acc[2] * (float)NC;
    out[0] = acc[0] / denom;              // loss_pos * W_POS(=1.0)
    out[1] = acc[1] / denom * 0.1f;       // loss_neg * W_NEG(=0.1)
}

extern "C" void kernel_launch(void* const* d_in, const int* in_sizes, int n_in,
                              void* d_out, int out_size, void* d_ws, size_t ws_size,
                              hipStream_t stream) {
    const float* trg = (const float*)d_in[0];   // [2,19,128,128]
    const float* ema = (const float*)d_in[1];   // [2,19,64,64]
    const float* xe  = (const float*)d_in[2];   // [2,64,32,32]
    const float* mix = (const float*)d_in[3];   // [2,1,128,128]
    float* acc = (float*)d_ws;
    float* out = (float*)d_out;

    hipLaunchKernelGGL(pfst_init, dim3(1), dim3(1), 0, stream, acc);
    // 4 lanes/pixel: 64 pixels per 256-thread block -> 512 blocks, 2048 waves.
    hipLaunchKernelGGL(pfst_main, dim3((NB * NH * NW) / 64), dim3(256), 0, stream,
                       trg, ema, xe, mix, acc);
    hipLaunchKernelGGL(pfst_final, dim3(1), dim3(1), 0, stream, acc, out);
}